// Round 9
// baseline (495.322 us; speedup 1.0000x reference)
//
#include <hip/hip_runtime.h>
#include <hip/hip_bf16.h>

// ---------- constants ----------
#define M_ROWS   11520          // b*n = 2*5760
#define D_IN     512
#define HD       1960
#define HDP      2048           // padded N for GEMM1 tiles
#define CPAD     52             // per-cch padded patch count (49 -> 52)
#define K2       2080           // 40*52, GEMM2 K
#define B2C      16
#define NVECS    720            // 20*36
#define LH       20
#define LW       36
#define HH       60
#define WW       108
#define CCH      40             // 1960/49

// virtual block counts per phase
#define NB_PREP  7776           // 5760 conv | 1024 w1t | 992 w2t
#define NB_G1    1440           // 90 x 16
#define NB_FU    1280           // 16*40*2
#define NB_G2    360            // 90 x 4

using bf16x8 = __attribute__((ext_vector_type(8))) short;
using f32x4  = __attribute__((ext_vector_type(4))) float;
using f4     = __attribute__((ext_vector_type(4))) float;
using su4    = __attribute__((ext_vector_type(4))) unsigned short;

__device__ __forceinline__ float bf2f(unsigned short u) {
    unsigned int x = ((unsigned int)u) << 16;
    return __builtin_bit_cast(float, x);
}
__device__ __forceinline__ unsigned short f2bf(float f) {
    unsigned int x = __builtin_bit_cast(unsigned int, f);
    unsigned int r = (x + 0x7fffu + ((x >> 16) & 1u)) >> 16;
    return (unsigned short)r;
}

// async global->LDS, 16 bytes per lane (global_load_lds_dwordx4)
__device__ __forceinline__ void gl_lds16(const unsigned short* g, unsigned short* l) {
    __builtin_amdgcn_global_load_lds(
        (const __attribute__((address_space(1))) unsigned int*)g,
        (__attribute__((address_space(3))) unsigned int*)l, 16, 0, 0);
}

// grid-wide barrier: all nblk blocks co-resident (grid sized via occupancy API).
// Counter pre-zeroed by hipMemsetAsync. Device-scope release/acquire handles
// cross-XCD L2 non-coherence (each block's wave0 executes the fences on its CU).
__device__ __forceinline__ void grid_barrier(unsigned* c, unsigned nblk) {
    __syncthreads();                      // per-thread vmcnt(0) drain before barrier
    if (threadIdx.x == 0) {
        __threadfence();                  // agent-scope release (L2 writeback)
        __hip_atomic_fetch_add(c, 1u, __ATOMIC_ACQ_REL, __HIP_MEMORY_SCOPE_AGENT);
        while (__hip_atomic_load(c, __ATOMIC_ACQUIRE, __HIP_MEMORY_SCOPE_AGENT) < nblk)
            __builtin_amdgcn_s_sleep(2);
        __threadfence();                  // agent-scope acquire (L1/L2 invalidate)
    }
    __syncthreads();
}

// ---------- fully fused pipeline: prep | GEMM1 | fold+unfold | GEMM2 ----------
__global__ __launch_bounds__(256) void fused_all(
    const float* __restrict__ x, const float* __restrict__ W1, const float* __restrict__ W2,
    const float* __restrict__ b1, const float* __restrict__ b2v,
    unsigned short* __restrict__ xb, unsigned short* __restrict__ w1t,
    unsigned short* __restrict__ w2t, unsigned short* __restrict__ h_blk,
    unsigned short* __restrict__ uf, float* __restrict__ outp,
    unsigned* __restrict__ cnt, unsigned nblk)
{
    __shared__ __align__(16) unsigned char lds_raw[52224];
    unsigned short* sA    = (unsigned short*)lds_raw;            // 8 KB (gemm)
    unsigned short* sB    = sA + 4096;                           // 8 KB (gemm)
    unsigned short* h_lds = (unsigned short*)lds_raw;            // 44,928 B (fold)
    unsigned short* y_lds = h_lds + 12 * 36 * CPAD;              //  7,128 B (fold)
    unsigned short (*tile)[33] = (unsigned short (*)[33])lds_raw; // 2,112 B (prep)

    int t    = threadIdx.x;
    int w    = t >> 6;
    int lane = t & 63;
    int quad = lane >> 4;
    int l16  = lane & 15;
    int wr = (w >> 1) * 64, wc = (w & 1) * 64;

    // ================= phase 0: prep =================
    for (int vb = blockIdx.x; vb < NB_PREP; vb += gridDim.x) {
        if (vb < 5760) {                          // x (f32) -> xb (bf16), 4/thread
            int i = vb * 256 + t;
            f4 v = ((const f4*)x)[i];
            su4 o;
            o.x = f2bf(v.x); o.y = f2bf(v.y); o.z = f2bf(v.z); o.w = f2bf(v.w);
            ((su4*)xb)[i] = o;
        } else if (vb < 6784) {                   // W1t[n*512+k] = W1[k*1960+n]
            int blk = vb - 5760;
            int kt = blk & 15, nt = blk >> 4;
            int k0 = kt * 32, n0 = nt * 32;
            int tx = t & 31, ty = t >> 5;
#pragma unroll
            for (int p = 0; p < 4; p++) {
                int k = k0 + ty + p * 8;
                int n = n0 + tx;
                tile[ty + p * 8][tx] = (n < HD) ? f2bf(W1[k * HD + n]) : (unsigned short)0;
            }
            __syncthreads();
#pragma unroll
            for (int p = 0; p < 4; p++) {
                int n = n0 + ty + p * 8;
                int k = k0 + tx;
                w1t[n * 512 + k] = tile[tx][ty + p * 8];
            }
            __syncthreads();                      // tile reused next vb
        } else {                                  // W2t[n*2080 + cch*52+kk] = W2[(cch*49+kk)*512+n]
            int blk = vb - 6784;                  // 62 kt x 16 nt
            int kt = blk % 62, nt = blk / 62;
            int k0 = kt * 32, n0 = nt * 32;
            int tx = t & 31, ty = t >> 5;
#pragma unroll
            for (int p = 0; p < 4; p++) {
                int k = k0 + ty + p * 8;
                int n = n0 + tx;
                tile[ty + p * 8][tx] = (k < HD) ? f2bf(W2[k * 512 + n]) : (unsigned short)0;
            }
            __syncthreads();
#pragma unroll
            for (int p = 0; p < 4; p++) {
                int n = n0 + ty + p * 8;
                int k = k0 + tx;
                if (k < HD) {
                    int cch = k / 49, kk = k - cch * 49;
                    w2t[n * K2 + cch * CPAD + kk] = tile[tx][ty + p * 8];
                }
            }
            __syncthreads();
        }
    }
    grid_barrier(&cnt[0], nblk);

    // ================= phase 1: GEMM1 -> h_blk =================
    for (int vb = blockIdx.x; vb < NB_G1; vb += gridDim.x) {
        int bx = vb & 15, by = vb >> 4;
        int row0 = by * 128, col0 = bx * 128;
        const int lda = D_IN, ldb = D_IN;

        const unsigned short* Ag = xb  + (size_t)(row0 + (t >> 2)) * lda + (t & 3) * 8;
        const unsigned short* Bg = w1t + (size_t)(col0 + (t >> 2)) * ldb + (t & 3) * 8;
        unsigned short* lA0 = sA + t * 8;
        unsigned short* lA1 = sA + 2048 + t * 8;
        unsigned short* lB0 = sB + t * 8;
        unsigned short* lB1 = sB + 2048 + t * 8;

        f32x4 acc[4][4] = {};
        for (int k0 = 0; k0 < D_IN; k0 += 32) {
            gl_lds16(Ag + k0, lA0);
            gl_lds16(Ag + (size_t)64 * lda + k0, lA1);
            gl_lds16(Bg + k0, lB0);
            gl_lds16(Bg + (size_t)64 * ldb + k0, lB1);
            __syncthreads();
            bf16x8 a[4], bfr[4];
#pragma unroll
            for (int i = 0; i < 4; i++)
                a[i] = *(const bf16x8*)(sA + (wr + i * 16 + l16) * 32 + quad * 8);
#pragma unroll
            for (int j = 0; j < 4; j++)
                bfr[j] = *(const bf16x8*)(sB + (wc + j * 16 + l16) * 32 + quad * 8);
#pragma unroll
            for (int i = 0; i < 4; i++)
#pragma unroll
                for (int j = 0; j < 4; j++)
                    acc[i][j] = __builtin_amdgcn_mfma_f32_16x16x32_bf16(a[i], bfr[j], acc[i][j], 0, 0, 0);
            __syncthreads();
        }

        int rowterm[16];
#pragma unroll
        for (int i = 0; i < 4; i++)
#pragma unroll
            for (int r = 0; r < 4; r++) {
                int row = row0 + wr + i * 16 + quad * 4 + r;
                int bb = row / NVECS;
                int sp = row - bb * NVECS;
                rowterm[i * 4 + r] = bb * (CCH * NVECS * CPAD) + sp * CPAD;
            }
#pragma unroll
        for (int j = 0; j < 4; j++) {
            int col = col0 + wc + j * 16 + l16;   // natural: col = cch*49 + kk
            if (col < HD) {
                int cch = col / 49, kk = col - cch * 49;
                int colterm = cch * (NVECS * CPAD) + kk;
                float bv = b1[col];
#pragma unroll
                for (int i = 0; i < 4; i++)
#pragma unroll
                    for (int r = 0; r < 4; r++)
                        h_blk[(size_t)rowterm[i * 4 + r] + colterm] = f2bf(acc[i][j][r] + bv);
            }
        }
    }
    grid_barrier(&cnt[1], nblk);

    // ================= phase 2: fold + norm + relu + unfold -> uf =================
    for (int vb = blockIdx.x; vb < NB_FU; vb += gridDim.x) {
        int half = vb & 1;
        int cch  = (vb >> 1) % CCH;
        int b2   = vb / (CCH * 2);

        int lh_base = half ? 8 : 0;
        int y0 = half ? 27 : 0;
        int ny = half ? 33 : 31;

        const su4* hsrc = (const su4*)(h_blk +
            ((size_t)(b2 * CCH + cch) * NVECS + lh_base * 36) * CPAD);
        su4* hd = (su4*)h_lds;
        for (int i = t; i < 12 * 36 * CPAD / 4; i += 256)
            hd[i] = hsrc[i];
        __syncthreads();

        for (int idx = t; idx < ny * WW; idx += 256) {
            int rr = idx / WW, c = idx - rr * WW;
            int r  = y0 + rr;
            int rp = r + 3, cp = c + 3;
            int q1 = rp / 3, rem1 = rp - q1 * 3;
            int q2 = cp / 3, rem2 = cp - q2 * 3;
            bool rv0 = (q1 <= 19);
            bool rv2 = (rem1 == 0) & (q1 >= 2);
            int sl0 = q1 - lh_base, sl1 = sl0 - 1, sl2 = sl0 - 2;
            int rofs0 = rem1 * 7, rofs1 = rofs0 + 21, rofs2 = rofs0 + 42;
            bool cv0 = (q2 <= 35);
            bool cv2 = (rem2 == 0) & (q2 >= 2);
            int lw0 = q2, lw1 = q2 - 1, lw2 = q2 - 2;
            int n1 = 1 + (int)rv0 + (int)rv2;
            int n2 = 1 + (int)cv0 + (int)cv2;
            float s = 0.0f;
#define FTERM(vr, sl, rofs, vc, lw, cofs) {                                   \
            bool vv = (vr) & (vc);                                            \
            int ad = vv ? (((sl) * 36 + (lw)) * CPAD + (rofs) + (cofs)) : 0;  \
            float val = bf2f(h_lds[ad]);                                      \
            s += vv ? val : 0.0f; }
            FTERM(rv0,  sl0, rofs0, cv0,  lw0, rem2)
            FTERM(rv0,  sl0, rofs0, true, lw1, rem2 + 3)
            FTERM(rv0,  sl0, rofs0, cv2,  lw2, rem2 + 6)
            FTERM(true, sl1, rofs1, cv0,  lw0, rem2)
            FTERM(true, sl1, rofs1, true, lw1, rem2 + 3)
            FTERM(true, sl1, rofs1, cv2,  lw2, rem2 + 6)
            FTERM(rv2,  sl2, rofs2, cv0,  lw0, rem2)
            FTERM(rv2,  sl2, rofs2, true, lw1, rem2 + 3)
            FTERM(rv2,  sl2, rofs2, cv2,  lw2, rem2 + 6)
#undef FTERM
            y_lds[idx] = f2bf(fmaxf(s / (float)(n1 * n2), 0.0f));
        }
        __syncthreads();

        int lh0 = 10 * half;
        for (int i = t; i < 360 * 13; i += 256) {
            int ri = i / 13, q = i - ri * 13;
            int lh = lh0 + ri / 36;
            int lw = ri % 36;
            int rb = 3 * lh - 3, cb = 3 * lw - 3;
            int j0 = q * 4;
            su4 o;
#pragma unroll
            for (int e = 0; e < 4; e++) {
                int j = j0 + e;
                unsigned short val = 0;
                if (j < 49) {
                    int k1 = j / 7, k2 = j - k1 * 7;
                    int r = rb + k1, cc = cb + k2;
                    if ((unsigned)r < (unsigned)HH && (unsigned)cc < (unsigned)WW)
                        val = y_lds[(r - y0) * WW + cc];
                }
                ((unsigned short*)&o)[e] = val;
            }
            int row = b2 * NVECS + lh * 36 + lw;
            *(su4*)(uf + (size_t)row * K2 + cch * CPAD + j0) = o;
        }
        __syncthreads();                          // LDS reused next vb
    }
    grid_barrier(&cnt[2], nblk);

    // ================= phase 3: GEMM2 -> out =================
    for (int vb = blockIdx.x; vb < NB_G2; vb += gridDim.x) {
        int bx = vb & 3, by = vb >> 2;
        int row0 = by * 128, col0 = bx * 128;
        const int lda = K2, ldb = K2;

        const unsigned short* Ag = uf  + (size_t)(row0 + (t >> 2)) * lda + (t & 3) * 8;
        const unsigned short* Bg = w2t + (size_t)(col0 + (t >> 2)) * ldb + (t & 3) * 8;
        unsigned short* lA0 = sA + t * 8;
        unsigned short* lA1 = sA + 2048 + t * 8;
        unsigned short* lB0 = sB + t * 8;
        unsigned short* lB1 = sB + 2048 + t * 8;

        f32x4 acc[4][4] = {};
        for (int k0 = 0; k0 < K2; k0 += 32) {
            gl_lds16(Ag + k0, lA0);
            gl_lds16(Ag + (size_t)64 * lda + k0, lA1);
            gl_lds16(Bg + k0, lB0);
            gl_lds16(Bg + (size_t)64 * ldb + k0, lB1);
            __syncthreads();
            bf16x8 a[4], bfr[4];
#pragma unroll
            for (int i = 0; i < 4; i++)
                a[i] = *(const bf16x8*)(sA + (wr + i * 16 + l16) * 32 + quad * 8);
#pragma unroll
            for (int j = 0; j < 4; j++)
                bfr[j] = *(const bf16x8*)(sB + (wc + j * 16 + l16) * 32 + quad * 8);
#pragma unroll
            for (int i = 0; i < 4; i++)
#pragma unroll
                for (int j = 0; j < 4; j++)
                    acc[i][j] = __builtin_amdgcn_mfma_f32_16x16x32_bf16(a[i], bfr[j], acc[i][j], 0, 0, 0);
            __syncthreads();
        }
#pragma unroll
        for (int j = 0; j < 4; j++) {
            int col = col0 + wc + j * 16 + l16;
            float bv = b2v[col];
#pragma unroll
            for (int i = 0; i < 4; i++) {
                int rbase = row0 + wr + i * 16 + quad * 4;
#pragma unroll
                for (int r = 0; r < 4; r++)
                    outp[(size_t)(rbase + r) * D_IN + col] = acc[i][j][r] + bv;
            }
        }
    }
}

// ---------- launch ----------
extern "C" void kernel_launch(void* const* d_in, const int* in_sizes, int n_in,
                              void* d_out, int out_size, void* d_ws, size_t ws_size,
                              hipStream_t stream) {
    const float* x   = (const float*)d_in[0];
    const float* W1  = (const float*)d_in[1];
    const float* b1  = (const float*)d_in[2];
    const float* W2  = (const float*)d_in[3];
    const float* b2f = (const float*)d_in[4];
    float* out = (float*)d_out;

    unsigned short* ws    = (unsigned short*)d_ws;
    unsigned short* xb    = ws;                                 // 11520*512
    unsigned short* h_blk = xb + (size_t)M_ROWS * D_IN;         // 11520*2080
    unsigned short* uf    = h_blk + (size_t)M_ROWS * K2;        // 11520*2080
    unsigned short* w1t   = uf + (size_t)M_ROWS * K2;           // 2048*512
    unsigned short* w2t   = w1t + (size_t)HDP * D_IN;           // 512*2080
    unsigned* cnt         = (unsigned*)(w2t + (size_t)D_IN * K2);

    // zero the 3 barrier counters (async, graph-capturable)
    hipMemsetAsync(cnt, 0, 16, stream);

    // grid sized to guaranteed co-residency (52 KB LDS -> expect 3 blocks/CU)
    int nb = 0;
    if (hipOccupancyMaxActiveBlocksPerMultiprocessor(&nb, (const void*)fused_all, 256, 0)
            != hipSuccess || nb < 1)
        nb = 1;
    if (nb > 3) nb = 3;
    unsigned grid = (unsigned)nb * 256u;

    hipLaunchKernelGGL(fused_all, dim3(grid), dim3(256), 0, stream,
                       x, W1, W2, b1, b2f, xb, w1t, w2t, h_blk, uf, out, cnt, grid);
}

// Round 10
// 242.327 us; speedup vs baseline: 2.0440x; 2.0440x over previous
//
#include <hip/hip_runtime.h>
#include <hip/hip_bf16.h>

// ---------- constants ----------
#define M_ROWS   11520          // b*n = 2*5760
#define D_IN     512
#define HD       1960
#define HDP      2048           // padded N for GEMM1 tiles
#define CPAD     52             // per-cch padded patch count (49 -> 52)
#define K2       2080           // 40*52, GEMM2 K
#define B2C      16
#define NVECS    720            // 20*36
#define LH       20
#define LW       36
#define HH       60
#define WW       108
#define CCH      40             // 1960/49

using bf16x8 = __attribute__((ext_vector_type(8))) short;
using f32x4  = __attribute__((ext_vector_type(4))) float;
using f4     = __attribute__((ext_vector_type(4))) float;
using su4    = __attribute__((ext_vector_type(4))) unsigned short;

__device__ __forceinline__ float bf2f(unsigned short u) {
    unsigned int x = ((unsigned int)u) << 16;
    return __builtin_bit_cast(float, x);
}
__device__ __forceinline__ unsigned short f2bf(float f) {
    unsigned int x = __builtin_bit_cast(unsigned int, f);
    unsigned int r = (x + 0x7fffu + ((x >> 16) & 1u)) >> 16;
    return (unsigned short)r;
}

// async global->LDS, 16 bytes per lane (global_load_lds_dwordx4)
__device__ __forceinline__ void gl_lds16(const unsigned short* g, unsigned short* l) {
    __builtin_amdgcn_global_load_lds(
        (const __attribute__((address_space(1))) unsigned int*)g,
        (__attribute__((address_space(3))) unsigned int*)l, 16, 0, 0);
}

// ---------- prep: conv x -> bf16 | pack W1t | pack W2t (52-relabel) ----------
__global__ __launch_bounds__(256) void prep(
    const float* __restrict__ x, const float* __restrict__ W1, const float* __restrict__ W2,
    unsigned short* __restrict__ xb, unsigned short* __restrict__ w1t,
    unsigned short* __restrict__ w2t)
{
    __shared__ unsigned short tile[32][33];
    int b = blockIdx.x, t = threadIdx.x;
    if (b < 5760) {                               // x (f32) -> xb (bf16), 4/thread
        int i = b * 256 + t;
        f4 v = ((const f4*)x)[i];
        su4 o;
        o.x = f2bf(v.x); o.y = f2bf(v.y); o.z = f2bf(v.z); o.w = f2bf(v.w);
        ((su4*)xb)[i] = o;
        return;
    }
    int tx = t & 31, ty = t >> 5;                 // ty in [0,8)
    if (b < 6784) {                               // W1t[n*512+k] = W1[k*1960+n]
        int blk = b - 5760;
        int kt = blk & 15, nt = blk >> 4;
        int k0 = kt * 32, n0 = nt * 32;
#pragma unroll
        for (int p = 0; p < 4; p++) {
            int k = k0 + ty + p * 8;
            int n = n0 + tx;
            tile[ty + p * 8][tx] = (n < HD) ? f2bf(W1[k * HD + n]) : (unsigned short)0;
        }
        __syncthreads();
#pragma unroll
        for (int p = 0; p < 4; p++) {
            int n = n0 + ty + p * 8;
            int k = k0 + tx;
            w1t[n * 512 + k] = tile[tx][ty + p * 8];
        }
    } else {                                      // W2t[n*2080 + cch*52+kk] = W2[(cch*49+kk)*512+n]
        int blk = b - 6784;                       // 62 kt x 16 nt
        int kt = blk % 62, nt = blk / 62;
        int k0 = kt * 32, n0 = nt * 32;
#pragma unroll
        for (int p = 0; p < 4; p++) {
            int k = k0 + ty + p * 8;
            int n = n0 + tx;
            tile[ty + p * 8][tx] = (k < HD) ? f2bf(W2[k * 512 + n]) : (unsigned short)0;
        }
        __syncthreads();
#pragma unroll
        for (int p = 0; p < 4; p++) {
            int n = n0 + ty + p * 8;
            int k = k0 + tx;
            if (k < HD) {
                int cch = k / 49, kk = k - cch * 49;
                w2t[n * K2 + cch * CPAD + kk] = tile[tx][ty + p * 8];
            }
        }
    }
}

// ---------- GEMM1 with LDS bank-conflict swizzle: h_blk = x @ W1 + b1 ----------
// LDS slot swizzle: 16B block (row, qb) lives at slot row*4 + ((qb + (row>>1)) & 3).
// Staging keeps contiguous t*16B LDS writes (gl_lds16 constraint); each thread's
// GLOBAL qb is permuted instead. Fragment reads land 2 lanes/bank-group (free).
__global__ __launch_bounds__(256) void gemm1_blk(
    const unsigned short* __restrict__ A,
    const unsigned short* __restrict__ Bt,
    const float* __restrict__ bias,
    unsigned short* __restrict__ h_blk)
{
    __shared__ unsigned short sA[128 * 32];
    __shared__ unsigned short sB[128 * 32];
    const int lda = D_IN, ldb = D_IN;

    int bid = blockIdx.x;
    int bx = bid & 15, by = bid >> 4;
    int t    = threadIdx.x;
    int w    = t >> 6;
    int lane = t & 63;
    int quad = lane >> 4;
    int l16  = lane & 15;
    int row0 = by * 128, col0 = bx * 128;
    int wr = (w >> 1) * 64, wc = (w & 1) * 64;

    int srow = t >> 2;
    int qb = ((t & 3) - ((srow >> 1) & 3)) & 3;   // global 16B-block this thread stages
    const unsigned short* Ag = A  + (size_t)(row0 + srow) * lda + qb * 8;
    const unsigned short* Bg = Bt + (size_t)(col0 + srow) * ldb + qb * 8;
    unsigned short* lA0 = sA + t * 8;
    unsigned short* lA1 = sA + 2048 + t * 8;
    unsigned short* lB0 = sB + t * 8;
    unsigned short* lB1 = sB + 2048 + t * 8;

    int xq = (quad + ((l16 >> 1) & 3)) & 3;       // swizzled read slot

    f32x4 acc[4][4] = {};

    for (int k0 = 0; k0 < D_IN; k0 += 32) {
        gl_lds16(Ag + k0, lA0);
        gl_lds16(Ag + (size_t)64 * lda + k0, lA1);
        gl_lds16(Bg + k0, lB0);
        gl_lds16(Bg + (size_t)64 * ldb + k0, lB1);
        __syncthreads();

        bf16x8 a[4], bfr[4];
#pragma unroll
        for (int i = 0; i < 4; i++)
            a[i] = *(const bf16x8*)(sA + (wr + i * 16 + l16) * 32 + xq * 8);
#pragma unroll
        for (int j = 0; j < 4; j++)
            bfr[j] = *(const bf16x8*)(sB + (wc + j * 16 + l16) * 32 + xq * 8);
#pragma unroll
        for (int i = 0; i < 4; i++)
#pragma unroll
            for (int j = 0; j < 4; j++)
                acc[i][j] = __builtin_amdgcn_mfma_f32_16x16x32_bf16(a[i], bfr[j], acc[i][j], 0, 0, 0);
        __syncthreads();
    }

    // row terms: addr = b2*1497600 + cch*37440 + sp*52 + kk
    int rowterm[16];
#pragma unroll
    for (int i = 0; i < 4; i++)
#pragma unroll
        for (int r = 0; r < 4; r++) {
            int row = row0 + wr + i * 16 + quad * 4 + r;
            int bb = row / NVECS;
            int sp = row - bb * NVECS;
            rowterm[i * 4 + r] = bb * (CCH * NVECS * CPAD) + sp * CPAD;
        }

#pragma unroll
    for (int j = 0; j < 4; j++) {
        int col = col0 + wc + j * 16 + l16;       // natural: col = cch*49 + kk
        if (col < HD) {
            int cch = col / 49, kk = col - cch * 49;
            int colterm = cch * (NVECS * CPAD) + kk;
            float bv = bias[col];
#pragma unroll
            for (int i = 0; i < 4; i++)
#pragma unroll
                for (int r = 0; r < 4; r++)
                    h_blk[(size_t)rowterm[i * 4 + r] + colterm] = f2bf(acc[i][j][r] + bv);
        }
    }
}

// ---------- fused fold+norm+relu+unfold: h_blk -> uf (M x 2080, 52-padded) ----------
__global__ __launch_bounds__(256) void fold_unfold(
    const unsigned short* __restrict__ h_blk,
    unsigned short* __restrict__ uf)
{
    __shared__ unsigned short h_lds[12 * 36 * CPAD];  // 44,928 B
    __shared__ unsigned short y_lds[33 * WW];         //  7,128 B
    int bid  = blockIdx.x;                            // 16*40*2 = 1280
    int half = bid & 1;
    int cch  = (bid >> 1) % CCH;
    int b2   = bid / (CCH * 2);
    int tid  = threadIdx.x;

    int lh_base = half ? 8 : 0;
    int y0 = half ? 27 : 0;
    int ny = half ? 33 : 31;

    const su4* hsrc = (const su4*)(h_blk +
        ((size_t)(b2 * CCH + cch) * NVECS + lh_base * 36) * CPAD);
    su4* hd = (su4*)h_lds;
    for (int i = tid; i < 12 * 36 * CPAD / 4; i += 256)
        hd[i] = hsrc[i];
    __syncthreads();

    for (int idx = tid; idx < ny * WW; idx += 256) {
        int rr = idx / WW, c = idx - rr * WW;
        int r  = y0 + rr;
        int rp = r + 3, cp = c + 3;
        int q1 = rp / 3, rem1 = rp - q1 * 3;
        int q2 = cp / 3, rem2 = cp - q2 * 3;
        bool rv0 = (q1 <= 19);
        bool rv2 = (rem1 == 0) & (q1 >= 2);
        int sl0 = q1 - lh_base, sl1 = sl0 - 1, sl2 = sl0 - 2;
        int rofs0 = rem1 * 7, rofs1 = rofs0 + 21, rofs2 = rofs0 + 42;
        bool cv0 = (q2 <= 35);
        bool cv2 = (rem2 == 0) & (q2 >= 2);
        int lw0 = q2, lw1 = q2 - 1, lw2 = q2 - 2;
        int n1 = 1 + (int)rv0 + (int)rv2;
        int n2 = 1 + (int)cv0 + (int)cv2;
        float s = 0.0f;
#define FTERM(vr, sl, rofs, vc, lw, cofs) {                                   \
        bool vv = (vr) & (vc);                                                \
        int ad = vv ? (((sl) * 36 + (lw)) * CPAD + (rofs) + (cofs)) : 0;      \
        float val = bf2f(h_lds[ad]);                                          \
        s += vv ? val : 0.0f; }
        FTERM(rv0,  sl0, rofs0, cv0,  lw0, rem2)
        FTERM(rv0,  sl0, rofs0, true, lw1, rem2 + 3)
        FTERM(rv0,  sl0, rofs0, cv2,  lw2, rem2 + 6)
        FTERM(true, sl1, rofs1, cv0,  lw0, rem2)
        FTERM(true, sl1, rofs1, true, lw1, rem2 + 3)
        FTERM(true, sl1, rofs1, cv2,  lw2, rem2 + 6)
        FTERM(rv2,  sl2, rofs2, cv0,  lw0, rem2)
        FTERM(rv2,  sl2, rofs2, true, lw1, rem2 + 3)
        FTERM(rv2,  sl2, rofs2, cv2,  lw2, rem2 + 6)
#undef FTERM
        y_lds[idx] = f2bf(fmaxf(s / (float)(n1 * n2), 0.0f));
    }
    __syncthreads();

    int lh0 = 10 * half;
    for (int i = tid; i < 360 * 13; i += 256) {
        int ri = i / 13, q = i - ri * 13;
        int lh = lh0 + ri / 36;
        int lw = ri % 36;
        int rb = 3 * lh - 3, cb = 3 * lw - 3;
        int j0 = q * 4;
        su4 o;
#pragma unroll
        for (int e = 0; e < 4; e++) {
            int j = j0 + e;
            unsigned short val = 0;
            if (j < 49) {
                int k1 = j / 7, k2 = j - k1 * 7;
                int r = rb + k1, cc = cb + k2;
                if ((unsigned)r < (unsigned)HH && (unsigned)cc < (unsigned)WW)
                    val = y_lds[(r - y0) * WW + cc];
            }
            ((unsigned short*)&o)[e] = val;
        }
        int row = b2 * NVECS + lh * 36 + lw;
        *(su4*)(uf + (size_t)row * K2 + cch * CPAD + j0) = o;
    }
}

// ---------- GEMM2 with LDS bank-conflict swizzle: out(f32) = uf @ W2t^T + b2 ----------
__global__ __launch_bounds__(256) void gemm2(
    const unsigned short* __restrict__ A,
    const unsigned short* __restrict__ Bt,
    const float* __restrict__ bias,
    float* __restrict__ C)
{
    __shared__ unsigned short sA[128 * 32];
    __shared__ unsigned short sB[128 * 32];
    const int lda = K2, ldb = K2, ldc = D_IN;

    int bid = blockIdx.x;
    int bx = bid & 3, by = bid >> 2;
    int t    = threadIdx.x;
    int w    = t >> 6;
    int lane = t & 63;
    int quad = lane >> 4;
    int l16  = lane & 15;
    int row0 = by * 128, col0 = bx * 128;
    int wr = (w >> 1) * 64, wc = (w & 1) * 64;

    int srow = t >> 2;
    int qb = ((t & 3) - ((srow >> 1) & 3)) & 3;
    const unsigned short* Ag = A  + (size_t)(row0 + srow) * lda + qb * 8;
    const unsigned short* Bg = Bt + (size_t)(col0 + srow) * ldb + qb * 8;
    unsigned short* lA0 = sA + t * 8;
    unsigned short* lA1 = sA + 2048 + t * 8;
    unsigned short* lB0 = sB + t * 8;
    unsigned short* lB1 = sB + 2048 + t * 8;

    int xq = (quad + ((l16 >> 1) & 3)) & 3;

    f32x4 acc[4][4] = {};

    for (int k0 = 0; k0 < K2; k0 += 32) {
        gl_lds16(Ag + k0, lA0);
        gl_lds16(Ag + (size_t)64 * lda + k0, lA1);
        gl_lds16(Bg + k0, lB0);
        gl_lds16(Bg + (size_t)64 * ldb + k0, lB1);
        __syncthreads();

        bf16x8 a[4], bfr[4];
#pragma unroll
        for (int i = 0; i < 4; i++)
            a[i] = *(const bf16x8*)(sA + (wr + i * 16 + l16) * 32 + xq * 8);
#pragma unroll
        for (int j = 0; j < 4; j++)
            bfr[j] = *(const bf16x8*)(sB + (wc + j * 16 + l16) * 32 + xq * 8);
#pragma unroll
        for (int i = 0; i < 4; i++)
#pragma unroll
            for (int j = 0; j < 4; j++)
                acc[i][j] = __builtin_amdgcn_mfma_f32_16x16x32_bf16(a[i], bfr[j], acc[i][j], 0, 0, 0);
        __syncthreads();
    }

#pragma unroll
    for (int j = 0; j < 4; j++) {
        int col = col0 + wc + j * 16 + l16;
        float bv = bias[col];
#pragma unroll
        for (int i = 0; i < 4; i++) {
            int rbase = row0 + wr + i * 16 + quad * 4;
#pragma unroll
            for (int r = 0; r < 4; r++)
                C[(size_t)(rbase + r) * ldc + col] = acc[i][j][r] + bv;
        }
    }
}

// ---------- launch ----------
extern "C" void kernel_launch(void* const* d_in, const int* in_sizes, int n_in,
                              void* d_out, int out_size, void* d_ws, size_t ws_size,
                              hipStream_t stream) {
    const float* x   = (const float*)d_in[0];
    const float* W1  = (const float*)d_in[1];
    const float* b1  = (const float*)d_in[2];
    const float* W2  = (const float*)d_in[3];
    const float* b2f = (const float*)d_in[4];
    float* out = (float*)d_out;

    unsigned short* ws    = (unsigned short*)d_ws;
    unsigned short* xb    = ws;                                 // 11520*512
    unsigned short* h_blk = xb + (size_t)M_ROWS * D_IN;         // 11520*2080
    unsigned short* uf    = h_blk + (size_t)M_ROWS * K2;        // 11520*2080
    unsigned short* w1t   = uf + (size_t)M_ROWS * K2;           // 2048*512
    unsigned short* w2t   = w1t + (size_t)HDP * D_IN;           // 512*2080

    // 1. prep: conv x, pack W1t, pack W2t (one dispatch)
    hipLaunchKernelGGL(prep, dim3(7776), dim3(256), 0, stream, x, W1, W2, xb, w1t, w2t);

    // 2. GEMM1 -> h_blk (blocked fold-friendly layout)
    hipLaunchKernelGGL(gemm1_blk, dim3((M_ROWS / 128) * (HDP / 128)), dim3(256), 0, stream,
                       xb, w1t, b1, h_blk);

    // 3. fused fold + normalize + relu + unfold -> uf (52-padded)
    hipLaunchKernelGGL(fold_unfold, dim3(B2C * CCH * 2), dim3(256), 0, stream, h_blk, uf);

    // 4. GEMM2 -> out (f32)
    hipLaunchKernelGGL(gemm2, dim3((M_ROWS / 128) * (D_IN / 128)), dim3(256), 0, stream,
                       uf, w2t, b2f, out);
}